// Round 2
// baseline (1168.428 us; speedup 1.0000x reference)
//
#include <hip/hip_runtime.h>

#define NUSERS 100000
#define NITEMS 50000
#define NNODES 150000
#define DIM 64
#define E0 600000
#define BB 8192
#define LW 1e-4f

__global__ void k_zero(float* __restrict__ p, int n) {
  int i = blockIdx.x * blockDim.x + threadIdx.x;
  if (i < n) p[i] = 0.0f;
}

// deg[dst] counting over the symmetrized edge list: each raw edge (u,i)
// contributes dst=u (reversed half) and dst=NUSERS+i (forward half).
__global__ void k_count_deg(const int* __restrict__ eu, const int* __restrict__ ei,
                            float* __restrict__ deg) {
  int e = blockIdx.x * blockDim.x + threadIdx.x;
  if (e < E0) {
    atomicAdd(&deg[eu[e]], 1.0f);
    atomicAdd(&deg[NUSERS + ei[e]], 1.0f);
  }
}

__global__ void k_dinv(float* __restrict__ deg) {
  int n = blockIdx.x * blockDim.x + threadIdx.x;
  if (n < NNODES) {
    float d = deg[n];
    deg[n] = d > 0.0f ? rsqrtf(d) : 0.0f;
  }
}

// One thread per (raw edge, dim). Handles both edge directions; w symmetric.
__global__ void k_spmm(const int* __restrict__ eu, const int* __restrict__ ei,
                       const float* __restrict__ dinv,
                       const float* __restrict__ hin, float* __restrict__ hout) {
  int idx = blockIdx.x * blockDim.x + threadIdx.x;
  if (idx >= E0 * DIM) return;
  int e = idx >> 6;
  int d = idx & 63;
  int u = eu[e];
  int i = NUSERS + ei[e];
  float w = dinv[u] * dinv[i];
  float hu = hin[u * DIM + d];
  float hi = hin[i * DIM + d];
  atomicAdd(&hout[i * DIM + d], w * hu);
  atomicAdd(&hout[u * DIM + d], w * hi);
}

// Accumulate gathered rows of h into per-batch embedding accumulators.
__global__ void k_batch_add(const int* __restrict__ usr, const int* __restrict__ pos,
                            const int* __restrict__ neg, const float* __restrict__ h,
                            float* __restrict__ gu, float* __restrict__ gp,
                            float* __restrict__ gn) {
  int idx = blockIdx.x * blockDim.x + threadIdx.x;
  if (idx >= BB * DIM) return;
  int b = idx >> 6;
  int d = idx & 63;
  gu[idx] += h[usr[b] * DIM + d];
  gp[idx] += h[(NUSERS + pos[b]) * DIM + d];
  gn[idx] += h[(NUSERS + neg[b]) * DIM + d];
}

// One 64-lane wave per batch row: dots + reg, wave shuffle reduce, atomics.
__global__ void k_loss(const float* __restrict__ gu, const float* __restrict__ gp,
                       const float* __restrict__ gn, float* __restrict__ prt) {
  int idx = blockIdx.x * blockDim.x + threadIdx.x;
  int b = idx >> 6;
  int lane = threadIdx.x & 63;
  if (b >= BB) return;
  const float s = 0.25f;  // mean over N_LAYERS+1 = 4
  float u = gu[idx] * s;
  float p = gp[idx] * s;
  float n = gn[idx] * s;
  float dp = u * p;
  float dn = u * n;
  float rg = u * u + p * p + n * n;
  for (int off = 32; off > 0; off >>= 1) {
    dp += __shfl_down(dp, off);
    dn += __shfl_down(dn, off);
    rg += __shfl_down(rg, off);
  }
  if (lane == 0) {
    float diff = dp - dn;
    // stable log_sigmoid(diff) = min(diff,0) - log1p(exp(-|diff|))
    float ls = fminf(diff, 0.0f) - log1pf(expf(-fabsf(diff)));
    atomicAdd(&prt[0], -ls);
    atomicAdd(&prt[1], rg);
  }
}

__global__ void k_final(const float* __restrict__ prt, float* __restrict__ out) {
  float mf = prt[0] * (1.0f / BB);
  float reg = LW * 0.5f * prt[1] * (1.0f / BB);
  out[0] = mf + reg;
}

extern "C" void kernel_launch(void* const* d_in, const int* in_sizes, int n_in,
                              void* d_out, int out_size, void* d_ws, size_t ws_size,
                              hipStream_t stream) {
  const float* Gu = (const float*)d_in[0];   // float32 per reference
  const float* Gi = (const float*)d_in[1];
  const int* eu  = (const int*)d_in[2];
  const int* ei  = (const int*)d_in[3];
  const int* usr = (const int*)d_in[4];
  const int* pos = (const int*)d_in[5];
  const int* neg = (const int*)d_in[6];
  float* out = (float*)d_out;                // float32 per reference

  // Workspace layout (floats). Total ~20.92M floats = 83.7 MB.
  float* W    = (float*)d_ws;
  float* dinv = W;                    // 150000 (padded to 150016)
  float* hA   = W + 150016;           // 9,600,000
  float* hB   = hA + NNODES * DIM;    // 9,600,000
  float* gu   = hB + NNODES * DIM;    // 524,288
  float* gp   = gu + BB * DIM;        // 524,288
  float* gn   = gp + BB * DIM;        // 524,288
  float* prt  = gn + BB * DIM;        // 2

  const int T = 256;
  auto cdiv = [](int a, int b) { return (a + b - 1) / b; };

  // zero deg and the contiguous batch accumulators + partials (gu..prt)
  k_zero<<<cdiv(NNODES, T), T, 0, stream>>>(dinv, NNODES);
  k_zero<<<cdiv(3 * BB * DIM + 2, T), T, 0, stream>>>(gu, 3 * BB * DIM + 2);

  k_count_deg<<<cdiv(E0, T), T, 0, stream>>>(eu, ei, dinv);
  k_dinv<<<cdiv(NNODES, T), T, 0, stream>>>(dinv);

  // h0 = concat(Gu, Gi) — plain D2D copies (graph-capture safe)
  hipMemcpyAsync(hA, Gu, (size_t)NUSERS * DIM * sizeof(float),
                 hipMemcpyDeviceToDevice, stream);
  hipMemcpyAsync(hA + (size_t)NUSERS * DIM, Gi, (size_t)NITEMS * DIM * sizeof(float),
                 hipMemcpyDeviceToDevice, stream);

  // layer-0 (x itself) contribution to the batch accumulators
  k_batch_add<<<cdiv(BB * DIM, T), T, 0, stream>>>(usr, pos, neg, hA, gu, gp, gn);

  float* cur = hA;
  float* nxt = hB;
  for (int l = 0; l < 3; ++l) {
    k_zero<<<cdiv(NNODES * DIM, T), T, 0, stream>>>(nxt, NNODES * DIM);
    k_spmm<<<cdiv(E0 * DIM, T), T, 0, stream>>>(eu, ei, dinv, cur, nxt);
    k_batch_add<<<cdiv(BB * DIM, T), T, 0, stream>>>(usr, pos, neg, nxt, gu, gp, gn);
    float* t = cur; cur = nxt; nxt = t;
  }

  k_loss<<<cdiv(BB * DIM, T), T, 0, stream>>>(gu, gp, gn, prt);
  k_final<<<1, 1, 0, stream>>>(prt, out);
}

// Round 3
// 640.328 us; speedup vs baseline: 1.8247x; 1.8247x over previous
//
#include <hip/hip_runtime.h>

#define NUSERS 100000
#define NITEMS 50000
#define NNODES 150000
#define DIM 64
#define E0 600000
#define E2 (2 * E0)
#define BB 8192
#define LW 1e-4f
#define NN16 150016
#define NB 586  // cdiv(NNODES, 256)

__global__ void k_zero_i(int* __restrict__ p, int n) {
  int i = blockIdx.x * blockDim.x + threadIdx.x;
  if (i < n) p[i] = 0;
}

__global__ void k_zero_f(float* __restrict__ p, int n) {
  int i = blockIdx.x * blockDim.x + threadIdx.x;
  if (i < n) p[i] = 0.0f;
}

__global__ void k_count_deg(const int* __restrict__ eu, const int* __restrict__ ei,
                            int* __restrict__ deg) {
  int e = blockIdx.x * blockDim.x + threadIdx.x;
  if (e < E0) {
    atomicAdd(&deg[eu[e]], 1);
    atomicAdd(&deg[NUSERS + ei[e]], 1);
  }
}

__global__ void k_dinv(const int* __restrict__ deg, float* __restrict__ dinv) {
  int n = blockIdx.x * blockDim.x + threadIdx.x;
  if (n < NNODES) {
    int d = deg[n];
    dinv[n] = d > 0 ? rsqrtf((float)d) : 0.0f;
  }
}

// --- 3-kernel exclusive scan over deg -> ptr ---
__global__ void k_scan1(const int* __restrict__ deg, int* __restrict__ ptr,
                        int* __restrict__ blk) {
  __shared__ int s[256];
  int g = blockIdx.x * 256 + threadIdx.x;
  int v = (g < NNODES) ? deg[g] : 0;
  s[threadIdx.x] = v;
  __syncthreads();
  for (int off = 1; off < 256; off <<= 1) {
    int t = 0;
    if ((int)threadIdx.x >= off) t = s[threadIdx.x - off];
    __syncthreads();
    if ((int)threadIdx.x >= off) s[threadIdx.x] += t;
    __syncthreads();
  }
  if (g < NNODES) ptr[g] = s[threadIdx.x] - v;  // exclusive
  if (threadIdx.x == 255) blk[blockIdx.x] = s[255];
}

__global__ void k_scan2(int* __restrict__ blk) {
  __shared__ int s[1024];
  int v = ((int)threadIdx.x < NB) ? blk[threadIdx.x] : 0;
  s[threadIdx.x] = v;
  __syncthreads();
  for (int off = 1; off < 1024; off <<= 1) {
    int t = 0;
    if ((int)threadIdx.x >= off) t = s[threadIdx.x - off];
    __syncthreads();
    if ((int)threadIdx.x >= off) s[threadIdx.x] += t;
    __syncthreads();
  }
  if ((int)threadIdx.x < NB) blk[threadIdx.x] = s[threadIdx.x] - v;  // exclusive
}

__global__ void k_scan3(int* __restrict__ ptr, const int* __restrict__ blk) {
  int g = blockIdx.x * 256 + threadIdx.x;
  if (g < NNODES) ptr[g] += blk[blockIdx.x];
}

// Fill CSR columns; advances ptr destructively (after: ptr[n] == row_end(n)).
__global__ void k_fill(const int* __restrict__ eu, const int* __restrict__ ei,
                       int* __restrict__ ptr, int* __restrict__ col) {
  int e = blockIdx.x * blockDim.x + threadIdx.x;
  if (e < E0) {
    int u = eu[e];
    int it = NUSERS + ei[e];
    col[atomicAdd(&ptr[u], 1)] = it;
    col[atomicAdd(&ptr[it], 1)] = u;
  }
}

// Gather-only SpMM. One wave per destination node. lane = 16*sub + q:
// sub in [0,4) walks neighbors stride-4, q in [0,16) covers dims via float4.
// User rows read from hu + c*16; item rows from hi + (c-NUSERS)*16.
__global__ void k_spmm_csr(const int* __restrict__ ptr, const int* __restrict__ deg,
                           const int* __restrict__ col, const float* __restrict__ dinv,
                           const float4* __restrict__ hu, const float4* __restrict__ hi,
                           float4* __restrict__ hout) {
  int tid = threadIdx.x;
  int n = blockIdx.x * 4 + (tid >> 6);
  if (n >= NNODES) return;
  int lane = tid & 63;
  int sub = lane >> 4;
  int q = lane & 15;
  int end = ptr[n];
  int start = end - deg[n];
  float dn = dinv[n];
  float4 acc = {0.0f, 0.0f, 0.0f, 0.0f};
  for (int j = start + sub; j < end; j += 4) {
    int c = col[j];
    float w = dn * dinv[c];
    const float4* base = (c < NUSERS) ? (hu + (size_t)c * 16)
                                      : (hi + (size_t)(c - NUSERS) * 16);
    float4 v = base[q];
    acc.x += w * v.x;
    acc.y += w * v.y;
    acc.z += w * v.z;
    acc.w += w * v.w;
  }
  // combine the 4 sub-partials (lanes q, q+16, q+32, q+48)
  acc.x += __shfl_xor(acc.x, 16); acc.y += __shfl_xor(acc.y, 16);
  acc.z += __shfl_xor(acc.z, 16); acc.w += __shfl_xor(acc.w, 16);
  acc.x += __shfl_xor(acc.x, 32); acc.y += __shfl_xor(acc.y, 32);
  acc.z += __shfl_xor(acc.z, 32); acc.w += __shfl_xor(acc.w, 32);
  if (sub == 0) hout[(size_t)n * 16 + q] = acc;
}

// Accumulate gathered rows into batch accumulators; float4 lanes, 16/row.
__global__ void k_batch_add(const int* __restrict__ usr, const int* __restrict__ pos,
                            const int* __restrict__ neg,
                            const float4* __restrict__ bu, const float4* __restrict__ bi,
                            float4* __restrict__ gu, float4* __restrict__ gp,
                            float4* __restrict__ gn) {
  int idx = blockIdx.x * blockDim.x + threadIdx.x;
  if (idx >= BB * 16) return;
  int b = idx >> 4;
  int q = idx & 15;
  float4 a = bu[(size_t)usr[b] * 16 + q];
  float4 p = bi[(size_t)pos[b] * 16 + q];
  float4 ng = bi[(size_t)neg[b] * 16 + q];
  float4 x;
  x = gu[idx]; x.x += a.x; x.y += a.y; x.z += a.z; x.w += a.w; gu[idx] = x;
  x = gp[idx]; x.x += p.x; x.y += p.y; x.z += p.z; x.w += p.w; gp[idx] = x;
  x = gn[idx]; x.x += ng.x; x.y += ng.y; x.z += ng.z; x.w += ng.w; gn[idx] = x;
}

__global__ void k_loss(const float* __restrict__ gu, const float* __restrict__ gp,
                       const float* __restrict__ gn, float* __restrict__ prt) {
  int idx = blockIdx.x * blockDim.x + threadIdx.x;
  int b = idx >> 6;
  int lane = threadIdx.x & 63;
  if (b >= BB) return;
  const float s = 0.25f;  // mean over N_LAYERS+1 = 4
  float u = gu[idx] * s;
  float p = gp[idx] * s;
  float n = gn[idx] * s;
  float dp = u * p;
  float dn = u * n;
  float rg = u * u + p * p + n * n;
  for (int off = 32; off > 0; off >>= 1) {
    dp += __shfl_down(dp, off);
    dn += __shfl_down(dn, off);
    rg += __shfl_down(rg, off);
  }
  if (lane == 0) {
    float diff = dp - dn;
    float ls = fminf(diff, 0.0f) - log1pf(expf(-fabsf(diff)));
    atomicAdd(&prt[0], -ls);
    atomicAdd(&prt[1], rg);
  }
}

__global__ void k_final(const float* __restrict__ prt, float* __restrict__ out) {
  float mf = prt[0] * (1.0f / BB);
  float reg = LW * 0.5f * prt[1] * (1.0f / BB);
  out[0] = mf + reg;
}

extern "C" void kernel_launch(void* const* d_in, const int* in_sizes, int n_in,
                              void* d_out, int out_size, void* d_ws, size_t ws_size,
                              hipStream_t stream) {
  const float* Gu = (const float*)d_in[0];
  const float* Gi = (const float*)d_in[1];
  const int* eu  = (const int*)d_in[2];
  const int* ei  = (const int*)d_in[3];
  const int* usr = (const int*)d_in[4];
  const int* pos = (const int*)d_in[5];
  const int* neg = (const int*)d_in[6];
  float* out = (float*)d_out;

  // Workspace layout: ~22.6M words = 90.3 MB
  int* deg   = (int*)d_ws;             // NN16
  int* ptrA  = deg + NN16;             // NN16
  int* blk   = ptrA + NN16;            // 1024
  int* col   = blk + 1024;             // E2
  float* dinv = (float*)(col + E2);    // NN16
  float* hA  = dinv + NN16;            // 9.6M
  float* hB  = hA + (size_t)NNODES * DIM;  // 9.6M
  float* gu  = hB + (size_t)NNODES * DIM;  // 524288
  float* gp  = gu + BB * DIM;
  float* gn  = gp + BB * DIM;
  float* prt = gn + BB * DIM;          // 2

  const int T = 256;
  auto cdiv = [](int a, int b) { return (a + b - 1) / b; };

  k_zero_i<<<cdiv(NN16, T), T, 0, stream>>>(deg, NN16);
  k_zero_f<<<cdiv(3 * BB * DIM + 2, T), T, 0, stream>>>(gu, 3 * BB * DIM + 2);

  k_count_deg<<<cdiv(E0, T), T, 0, stream>>>(eu, ei, deg);
  k_dinv<<<cdiv(NNODES, T), T, 0, stream>>>(deg, dinv);

  k_scan1<<<NB, 256, 0, stream>>>(deg, ptrA, blk);
  k_scan2<<<1, 1024, 0, stream>>>(blk);
  k_scan3<<<NB, 256, 0, stream>>>(ptrA, blk);
  k_fill<<<cdiv(E0, T), T, 0, stream>>>(eu, ei, ptrA, col);

  const float4* Gu4 = (const float4*)Gu;
  const float4* Gi4 = (const float4*)Gi;
  float4* hA4 = (float4*)hA;
  float4* hB4 = (float4*)hB;
  float4* gu4 = (float4*)gu;
  float4* gp4 = (float4*)gp;
  float4* gn4 = (float4*)gn;
  const size_t IOFF = (size_t)NUSERS * 16;  // item base offset in float4 units

  // layer 0 contribution (reads the inputs directly)
  k_batch_add<<<cdiv(BB * 16, T), T, 0, stream>>>(usr, pos, neg, Gu4, Gi4, gu4, gp4, gn4);

  // L1: inputs -> hA
  k_spmm_csr<<<cdiv(NNODES, 4), 256, 0, stream>>>(ptrA, deg, col, dinv, Gu4, Gi4, hA4);
  k_batch_add<<<cdiv(BB * 16, T), T, 0, stream>>>(usr, pos, neg, hA4, hA4 + IOFF, gu4, gp4, gn4);
  // L2: hA -> hB
  k_spmm_csr<<<cdiv(NNODES, 4), 256, 0, stream>>>(ptrA, deg, col, dinv, hA4, hA4 + IOFF, hB4);
  k_batch_add<<<cdiv(BB * 16, T), T, 0, stream>>>(usr, pos, neg, hB4, hB4 + IOFF, gu4, gp4, gn4);
  // L3: hB -> hA
  k_spmm_csr<<<cdiv(NNODES, 4), 256, 0, stream>>>(ptrA, deg, col, dinv, hB4, hB4 + IOFF, hA4);
  k_batch_add<<<cdiv(BB * 16, T), T, 0, stream>>>(usr, pos, neg, hA4, hA4 + IOFF, gu4, gp4, gn4);

  k_loss<<<cdiv(BB * DIM, T), T, 0, stream>>>(gu, gp, gn, prt);
  k_final<<<1, 1, 0, stream>>>(prt, out);
}

// Round 4
// 451.685 us; speedup vs baseline: 2.5868x; 1.4176x over previous
//
#include <hip/hip_runtime.h>

#define NUSERS 100000
#define NITEMS 50000
#define NNODES 150000
#define DIM 64
#define E0 600000
#define E2 (2 * E0)
#define BB 8192
#define LW 1e-4f
#define NN16 150016
#define NB 586  // cdiv(NNODES, 256)
#define LOSS_BLOCKS 128

__global__ void k_zero_i(int* __restrict__ p, int n) {
  int i = blockIdx.x * blockDim.x + threadIdx.x;
  if (i < n) p[i] = 0;
}

__global__ void k_zero_f(float* __restrict__ p, int n) {
  int i = blockIdx.x * blockDim.x + threadIdx.x;
  if (i < n) p[i] = 0.0f;
}

__global__ void k_count_deg(const int* __restrict__ eu, const int* __restrict__ ei,
                            int* __restrict__ deg) {
  int e = blockIdx.x * blockDim.x + threadIdx.x;
  if (e < E0) {
    atomicAdd(&deg[eu[e]], 1);
    atomicAdd(&deg[NUSERS + ei[e]], 1);
  }
}

__global__ void k_dinv(const int* __restrict__ deg, float* __restrict__ dinv) {
  int n = blockIdx.x * blockDim.x + threadIdx.x;
  if (n < NNODES) {
    int d = deg[n];
    dinv[n] = d > 0 ? rsqrtf((float)d) : 0.0f;
  }
}

// --- 3-kernel exclusive scan over deg -> ptr ---
__global__ void k_scan1(const int* __restrict__ deg, int* __restrict__ ptr,
                        int* __restrict__ blk) {
  __shared__ int s[256];
  int g = blockIdx.x * 256 + threadIdx.x;
  int v = (g < NNODES) ? deg[g] : 0;
  s[threadIdx.x] = v;
  __syncthreads();
  for (int off = 1; off < 256; off <<= 1) {
    int t = 0;
    if ((int)threadIdx.x >= off) t = s[threadIdx.x - off];
    __syncthreads();
    if ((int)threadIdx.x >= off) s[threadIdx.x] += t;
    __syncthreads();
  }
  if (g < NNODES) ptr[g] = s[threadIdx.x] - v;  // exclusive
  if (threadIdx.x == 255) blk[blockIdx.x] = s[255];
}

__global__ void k_scan2(int* __restrict__ blk) {
  __shared__ int s[1024];
  int v = ((int)threadIdx.x < NB) ? blk[threadIdx.x] : 0;
  s[threadIdx.x] = v;
  __syncthreads();
  for (int off = 1; off < 1024; off <<= 1) {
    int t = 0;
    if ((int)threadIdx.x >= off) t = s[threadIdx.x - off];
    __syncthreads();
    if ((int)threadIdx.x >= off) s[threadIdx.x] += t;
    __syncthreads();
  }
  if ((int)threadIdx.x < NB) blk[threadIdx.x] = s[threadIdx.x] - v;  // exclusive
}

__global__ void k_scan3(int* __restrict__ ptr, const int* __restrict__ blk) {
  int g = blockIdx.x * 256 + threadIdx.x;
  if (g < NNODES) ptr[g] += blk[blockIdx.x];
}

// Fill CSR columns; advances ptr destructively (after: ptr[n] == row_end(n)).
__global__ void k_fill(const int* __restrict__ eu, const int* __restrict__ ei,
                       int* __restrict__ ptr, int* __restrict__ col) {
  int e = blockIdx.x * blockDim.x + threadIdx.x;
  if (e < E0) {
    int u = eu[e];
    int it = NUSERS + ei[e];
    col[atomicAdd(&ptr[u], 1)] = it;
    col[atomicAdd(&ptr[it], 1)] = u;
  }
}

// Gather-only SpMM. One wave per destination node. lane = 16*sub + q:
// sub in [0,4) walks neighbors stride-4, q in [0,16) covers dims via float4.
__global__ void k_spmm_csr(const int* __restrict__ ptr, const int* __restrict__ deg,
                           const int* __restrict__ col, const float* __restrict__ dinv,
                           const float4* __restrict__ hu, const float4* __restrict__ hi,
                           float4* __restrict__ hout) {
  int tid = threadIdx.x;
  int n = blockIdx.x * 4 + (tid >> 6);
  if (n >= NNODES) return;
  int lane = tid & 63;
  int sub = lane >> 4;
  int q = lane & 15;
  int end = ptr[n];
  int start = end - deg[n];
  float dn = dinv[n];
  float4 acc = {0.0f, 0.0f, 0.0f, 0.0f};
  for (int j = start + sub; j < end; j += 4) {
    int c = col[j];
    float w = dn * dinv[c];
    const float4* base = (c < NUSERS) ? (hu + (size_t)c * 16)
                                      : (hi + (size_t)(c - NUSERS) * 16);
    float4 v = base[q];
    acc.x += w * v.x;
    acc.y += w * v.y;
    acc.z += w * v.z;
    acc.w += w * v.w;
  }
  acc.x += __shfl_xor(acc.x, 16); acc.y += __shfl_xor(acc.y, 16);
  acc.z += __shfl_xor(acc.z, 16); acc.w += __shfl_xor(acc.w, 16);
  acc.x += __shfl_xor(acc.x, 32); acc.y += __shfl_xor(acc.y, 32);
  acc.z += __shfl_xor(acc.z, 32); acc.w += __shfl_xor(acc.w, 32);
  if (sub == 0) hout[(size_t)n * 16 + q] = acc;
}

// Accumulate gathered rows into batch accumulators; float4 lanes, 16/row.
__global__ void k_batch_add(const int* __restrict__ usr, const int* __restrict__ pos,
                            const int* __restrict__ neg,
                            const float4* __restrict__ bu, const float4* __restrict__ bi,
                            float4* __restrict__ gu, float4* __restrict__ gp,
                            float4* __restrict__ gn) {
  int idx = blockIdx.x * blockDim.x + threadIdx.x;
  if (idx >= BB * 16) return;
  int b = idx >> 4;
  int q = idx & 15;
  float4 a = bu[(size_t)usr[b] * 16 + q];
  float4 p = bi[(size_t)pos[b] * 16 + q];
  float4 ng = bi[(size_t)neg[b] * 16 + q];
  float4 x;
  x = gu[idx]; x.x += a.x; x.y += a.y; x.z += a.z; x.w += a.w; gu[idx] = x;
  x = gp[idx]; x.x += p.x; x.y += p.y; x.z += p.z; x.w += p.w; gp[idx] = x;
  x = gn[idx]; x.x += ng.x; x.y += ng.y; x.z += ng.z; x.w += ng.w; gn[idx] = x;
}

// Grid-stride wave-per-row loss; NO global atomics. Block partials -> bpart.
// bpart layout: [0,LOSS_BLOCKS) = -sum log_sigmoid; [LOSS_BLOCKS, 2*LB) = reg.
__global__ void k_loss(const float* __restrict__ gu, const float* __restrict__ gp,
                       const float* __restrict__ gn, float* __restrict__ bpart) {
  __shared__ float sL[4], sR[4];
  int wid = threadIdx.x >> 6;
  int lane = threadIdx.x & 63;
  int gwave = blockIdx.x * 4 + wid;
  int nwaves = gridDim.x * 4;
  const float s = 0.25f;  // mean over N_LAYERS+1 = 4
  float accL = 0.0f, accR = 0.0f;
  for (int b = gwave; b < BB; b += nwaves) {
    int idx = b * 64 + lane;
    float u = gu[idx] * s;
    float p = gp[idx] * s;
    float n = gn[idx] * s;
    float dp = u * p;
    float dn = u * n;
    float rg = u * u + p * p + n * n;
    for (int off = 32; off > 0; off >>= 1) {
      dp += __shfl_down(dp, off);
      dn += __shfl_down(dn, off);
      rg += __shfl_down(rg, off);
    }
    if (lane == 0) {
      float diff = dp - dn;
      float ls = fminf(diff, 0.0f) - log1pf(expf(-fabsf(diff)));
      accL -= ls;
      accR += rg;
    }
  }
  if (lane == 0) { sL[wid] = accL; sR[wid] = accR; }
  __syncthreads();
  if (threadIdx.x == 0) {
    bpart[blockIdx.x] = sL[0] + sL[1] + sL[2] + sL[3];
    bpart[LOSS_BLOCKS + blockIdx.x] = sR[0] + sR[1] + sR[2] + sR[3];
  }
}

// One wave reduces the 128+128 block partials.
__global__ void k_final(const float* __restrict__ bpart, float* __restrict__ out) {
  int lane = threadIdx.x;
  float l = bpart[lane] + bpart[lane + 64];
  float r = bpart[LOSS_BLOCKS + lane] + bpart[LOSS_BLOCKS + lane + 64];
  for (int off = 32; off > 0; off >>= 1) {
    l += __shfl_down(l, off);
    r += __shfl_down(r, off);
  }
  if (lane == 0) out[0] = l * (1.0f / BB) + LW * 0.5f * r * (1.0f / BB);
}

extern "C" void kernel_launch(void* const* d_in, const int* in_sizes, int n_in,
                              void* d_out, int out_size, void* d_ws, size_t ws_size,
                              hipStream_t stream) {
  const float* Gu = (const float*)d_in[0];
  const float* Gi = (const float*)d_in[1];
  const int* eu  = (const int*)d_in[2];
  const int* ei  = (const int*)d_in[3];
  const int* usr = (const int*)d_in[4];
  const int* pos = (const int*)d_in[5];
  const int* neg = (const int*)d_in[6];
  float* out = (float*)d_out;

  int* deg   = (int*)d_ws;             // NN16
  int* ptrA  = deg + NN16;             // NN16
  int* blk   = ptrA + NN16;            // 1024
  int* col   = blk + 1024;             // E2
  float* dinv = (float*)(col + E2);    // NN16
  float* hA  = dinv + NN16;            // 9.6M
  float* hB  = hA + (size_t)NNODES * DIM;  // 9.6M
  float* gu  = hB + (size_t)NNODES * DIM;  // 524288
  float* gp  = gu + BB * DIM;
  float* gn  = gp + BB * DIM;
  float* bpart = gn + BB * DIM;        // 2*LOSS_BLOCKS

  const int T = 256;
  auto cdiv = [](int a, int b) { return (a + b - 1) / b; };

  k_zero_i<<<cdiv(NN16, T), T, 0, stream>>>(deg, NN16);
  k_zero_f<<<cdiv(3 * BB * DIM, T), T, 0, stream>>>(gu, 3 * BB * DIM);

  k_count_deg<<<cdiv(E0, T), T, 0, stream>>>(eu, ei, deg);
  k_dinv<<<cdiv(NNODES, T), T, 0, stream>>>(deg, dinv);

  k_scan1<<<NB, 256, 0, stream>>>(deg, ptrA, blk);
  k_scan2<<<1, 1024, 0, stream>>>(blk);
  k_scan3<<<NB, 256, 0, stream>>>(ptrA, blk);
  k_fill<<<cdiv(E0, T), T, 0, stream>>>(eu, ei, ptrA, col);

  const float4* Gu4 = (const float4*)Gu;
  const float4* Gi4 = (const float4*)Gi;
  float4* hA4 = (float4*)hA;
  float4* hB4 = (float4*)hB;
  float4* gu4 = (float4*)gu;
  float4* gp4 = (float4*)gp;
  float4* gn4 = (float4*)gn;
  const size_t IOFF = (size_t)NUSERS * 16;

  k_batch_add<<<cdiv(BB * 16, T), T, 0, stream>>>(usr, pos, neg, Gu4, Gi4, gu4, gp4, gn4);

  k_spmm_csr<<<cdiv(NNODES, 4), 256, 0, stream>>>(ptrA, deg, col, dinv, Gu4, Gi4, hA4);
  k_batch_add<<<cdiv(BB * 16, T), T, 0, stream>>>(usr, pos, neg, hA4, hA4 + IOFF, gu4, gp4, gn4);
  k_spmm_csr<<<cdiv(NNODES, 4), 256, 0, stream>>>(ptrA, deg, col, dinv, hA4, hA4 + IOFF, hB4);
  k_batch_add<<<cdiv(BB * 16, T), T, 0, stream>>>(usr, pos, neg, hB4, hB4 + IOFF, gu4, gp4, gn4);
  k_spmm_csr<<<cdiv(NNODES, 4), 256, 0, stream>>>(ptrA, deg, col, dinv, hB4, hB4 + IOFF, hA4);
  k_batch_add<<<cdiv(BB * 16, T), T, 0, stream>>>(usr, pos, neg, hA4, hA4 + IOFF, gu4, gp4, gn4);

  k_loss<<<LOSS_BLOCKS, 256, 0, stream>>>(gu, gp, gn, bpart);
  k_final<<<1, 64, 0, stream>>>(bpart, out);
}

// Round 5
// 414.252 us; speedup vs baseline: 2.8206x; 1.0904x over previous
//
#include <hip/hip_runtime.h>

#define NUSERS 100000
#define NITEMS 50000
#define NNODES 150000
#define DIM 64
#define E0 600000
#define E2 (2 * E0)
#define BB 8192
#define LW 1e-4f
#define NN16 150016
#define NB 586  // cdiv(NNODES, 256)
#define LOSS_BLOCKS 128

// ---- bf16 helpers (fp32 <-> packed bf16 pair in a uint) ----
__device__ __forceinline__ float bf_lo(unsigned u) { return __uint_as_float(u << 16); }
__device__ __forceinline__ float bf_hi(unsigned u) { return __uint_as_float(u & 0xffff0000u); }
__device__ __forceinline__ unsigned rne16(float x) {
  unsigned u = __float_as_uint(x);
  return (u + 0x7fffu + ((u >> 16) & 1u)) >> 16;
}
__device__ __forceinline__ unsigned pack2(float lo, float hi) {
  return rne16(lo) | (rne16(hi) << 16);
}

__global__ void k_zero_i(int* __restrict__ p, int n) {
  int i = blockIdx.x * blockDim.x + threadIdx.x;
  if (i < n) p[i] = 0;
}

// Count degrees; the atomic return value IS the edge's rank within its row.
__global__ void k_count_deg(const int* __restrict__ eu, const int* __restrict__ ei,
                            int* __restrict__ deg, int* __restrict__ ru,
                            int* __restrict__ ri) {
  int e = blockIdx.x * blockDim.x + threadIdx.x;
  if (e < E0) {
    ru[e] = atomicAdd(&deg[eu[e]], 1);
    ri[e] = atomicAdd(&deg[NUSERS + ei[e]], 1);
  }
}

// --- 3-kernel exclusive scan over deg -> ptr (row starts, non-destructive) ---
__global__ void k_scan1(const int* __restrict__ deg, int* __restrict__ ptr,
                        int* __restrict__ blk) {
  __shared__ int s[256];
  int g = blockIdx.x * 256 + threadIdx.x;
  int v = (g < NNODES) ? deg[g] : 0;
  s[threadIdx.x] = v;
  __syncthreads();
  for (int off = 1; off < 256; off <<= 1) {
    int t = 0;
    if ((int)threadIdx.x >= off) t = s[threadIdx.x - off];
    __syncthreads();
    if ((int)threadIdx.x >= off) s[threadIdx.x] += t;
    __syncthreads();
  }
  if (g < NNODES) ptr[g] = s[threadIdx.x] - v;  // exclusive
  if (threadIdx.x == 255) blk[blockIdx.x] = s[255];
}

__global__ void k_scan2(int* __restrict__ blk) {
  __shared__ int s[1024];
  int v = ((int)threadIdx.x < NB) ? blk[threadIdx.x] : 0;
  s[threadIdx.x] = v;
  __syncthreads();
  for (int off = 1; off < 1024; off <<= 1) {
    int t = 0;
    if ((int)threadIdx.x >= off) t = s[threadIdx.x - off];
    __syncthreads();
    if ((int)threadIdx.x >= off) s[threadIdx.x] += t;
    __syncthreads();
  }
  if ((int)threadIdx.x < NB) blk[threadIdx.x] = s[threadIdx.x] - v;  // exclusive
}

// scan fixup + dinv fused (both are per-node, NNODES-sized)
__global__ void k_scan3(int* __restrict__ ptr, const int* __restrict__ blk,
                        const int* __restrict__ deg, float* __restrict__ dinv) {
  int g = blockIdx.x * 256 + threadIdx.x;
  if (g < NNODES) {
    ptr[g] += blk[blockIdx.x];
    int d = deg[g];
    dinv[g] = d > 0 ? rsqrtf((float)d) : 0.0f;
  }
}

// Place CSR columns using precomputed ranks — NO atomics.
__global__ void k_place(const int* __restrict__ eu, const int* __restrict__ ei,
                        const int* __restrict__ ptr, const int* __restrict__ ru,
                        const int* __restrict__ ri, int* __restrict__ col) {
  int e = blockIdx.x * blockDim.x + threadIdx.x;
  if (e < E0) {
    int u = eu[e];
    int it = NUSERS + ei[e];
    col[ptr[u] + ru[e]] = it;
    col[ptr[it] + ri[e]] = u;
  }
}

// h0 (bf16, concat users|items) from the fp32 inputs. One float4 -> uint2/lane.
__global__ void k_cast(const float4* __restrict__ Gu4, const float4* __restrict__ Gi4,
                       uint2* __restrict__ h0) {
  int t = blockIdx.x * blockDim.x + threadIdx.x;
  if (t >= NNODES * 16) return;
  float4 v = (t < NUSERS * 16) ? Gu4[t] : Gi4[t - NUSERS * 16];
  h0[t] = make_uint2(pack2(v.x, v.y), pack2(v.z, v.w));
}

// Gather-only SpMM, bf16 in / bf16 out, fp32 accumulate.
// One wave per node: lane = 16*sub + q; sub walks neighbors stride-4,
// q indexes 16 uint2 (8 B) chunks of the 128 B row.
__global__ void k_spmm_bf(const int* __restrict__ ptr, const int* __restrict__ deg,
                          const int* __restrict__ col, const float* __restrict__ dinv,
                          const uint2* __restrict__ h, uint2* __restrict__ hout) {
  int tid = threadIdx.x;
  int n = blockIdx.x * 4 + (tid >> 6);
  if (n >= NNODES) return;
  int lane = tid & 63;
  int sub = lane >> 4;
  int q = lane & 15;
  int start = ptr[n];
  int end = start + deg[n];
  float dn = dinv[n];
  float a0 = 0.0f, a1 = 0.0f, a2 = 0.0f, a3 = 0.0f;
  for (int j = start + sub; j < end; j += 4) {
    int c = col[j];
    float w = dn * dinv[c];
    uint2 v = h[(size_t)c * 16 + q];
    a0 += w * bf_lo(v.x);
    a1 += w * bf_hi(v.x);
    a2 += w * bf_lo(v.y);
    a3 += w * bf_hi(v.y);
  }
  a0 += __shfl_xor(a0, 16); a1 += __shfl_xor(a1, 16);
  a2 += __shfl_xor(a2, 16); a3 += __shfl_xor(a3, 16);
  a0 += __shfl_xor(a0, 32); a1 += __shfl_xor(a1, 32);
  a2 += __shfl_xor(a2, 32); a3 += __shfl_xor(a3, 32);
  if (sub == 0) hout[(size_t)n * 16 + q] = make_uint2(pack2(a0, a1), pack2(a2, a3));
}

// Layer-0: SET batch accumulators from the fp32 inputs (replaces zeroing).
__global__ void k_batch_set(const int* __restrict__ usr, const int* __restrict__ pos,
                            const int* __restrict__ neg,
                            const float4* __restrict__ Gu4, const float4* __restrict__ Gi4,
                            float4* __restrict__ gu, float4* __restrict__ gp,
                            float4* __restrict__ gn) {
  int idx = blockIdx.x * blockDim.x + threadIdx.x;
  if (idx >= BB * 16) return;
  int b = idx >> 4;
  int q = idx & 15;
  gu[idx] = Gu4[(size_t)usr[b] * 16 + q];
  gp[idx] = Gi4[(size_t)pos[b] * 16 + q];
  gn[idx] = Gi4[(size_t)neg[b] * 16 + q];
}

// Layers 1..3: accumulate gathered bf16 rows into fp32 batch accumulators.
__global__ void k_batch_add(const int* __restrict__ usr, const int* __restrict__ pos,
                            const int* __restrict__ neg, const uint2* __restrict__ h,
                            float4* __restrict__ gu, float4* __restrict__ gp,
                            float4* __restrict__ gn) {
  int idx = blockIdx.x * blockDim.x + threadIdx.x;
  if (idx >= BB * 16) return;
  int b = idx >> 4;
  int q = idx & 15;
  uint2 a = h[(size_t)usr[b] * 16 + q];
  uint2 p = h[((size_t)NUSERS + pos[b]) * 16 + q];
  uint2 g = h[((size_t)NUSERS + neg[b]) * 16 + q];
  float4 x;
  x = gu[idx];
  x.x += bf_lo(a.x); x.y += bf_hi(a.x); x.z += bf_lo(a.y); x.w += bf_hi(a.y);
  gu[idx] = x;
  x = gp[idx];
  x.x += bf_lo(p.x); x.y += bf_hi(p.x); x.z += bf_lo(p.y); x.w += bf_hi(p.y);
  gp[idx] = x;
  x = gn[idx];
  x.x += bf_lo(g.x); x.y += bf_hi(g.x); x.z += bf_lo(g.y); x.w += bf_hi(g.y);
  gn[idx] = x;
}

// Grid-stride wave-per-row loss; no global atomics. Block partials -> bpart.
__global__ void k_loss(const float* __restrict__ gu, const float* __restrict__ gp,
                       const float* __restrict__ gn, float* __restrict__ bpart) {
  __shared__ float sL[4], sR[4];
  int wid = threadIdx.x >> 6;
  int lane = threadIdx.x & 63;
  int gwave = blockIdx.x * 4 + wid;
  int nwaves = gridDim.x * 4;
  const float s = 0.25f;  // mean over N_LAYERS+1 = 4
  float accL = 0.0f, accR = 0.0f;
  for (int b = gwave; b < BB; b += nwaves) {
    int idx = b * 64 + lane;
    float u = gu[idx] * s;
    float p = gp[idx] * s;
    float n = gn[idx] * s;
    float dp = u * p;
    float dn = u * n;
    float rg = u * u + p * p + n * n;
    for (int off = 32; off > 0; off >>= 1) {
      dp += __shfl_down(dp, off);
      dn += __shfl_down(dn, off);
      rg += __shfl_down(rg, off);
    }
    if (lane == 0) {
      float diff = dp - dn;
      float ls = fminf(diff, 0.0f) - log1pf(expf(-fabsf(diff)));
      accL -= ls;
      accR += rg;
    }
  }
  if (lane == 0) { sL[wid] = accL; sR[wid] = accR; }
  __syncthreads();
  if (threadIdx.x == 0) {
    bpart[blockIdx.x] = sL[0] + sL[1] + sL[2] + sL[3];
    bpart[LOSS_BLOCKS + blockIdx.x] = sR[0] + sR[1] + sR[2] + sR[3];
  }
}

__global__ void k_final(const float* __restrict__ bpart, float* __restrict__ out) {
  int lane = threadIdx.x;
  float l = bpart[lane] + bpart[lane + 64];
  float r = bpart[LOSS_BLOCKS + lane] + bpart[LOSS_BLOCKS + lane + 64];
  for (int off = 32; off > 0; off >>= 1) {
    l += __shfl_down(l, off);
    r += __shfl_down(r, off);
  }
  if (lane == 0) out[0] = l * (1.0f / BB) + LW * 0.5f * r * (1.0f / BB);
}

extern "C" void kernel_launch(void* const* d_in, const int* in_sizes, int n_in,
                              void* d_out, int out_size, void* d_ws, size_t ws_size,
                              hipStream_t stream) {
  const float* Gu = (const float*)d_in[0];
  const float* Gi = (const float*)d_in[1];
  const int* eu  = (const int*)d_in[2];
  const int* ei  = (const int*)d_in[3];
  const int* usr = (const int*)d_in[4];
  const int* pos = (const int*)d_in[5];
  const int* neg = (const int*)d_in[6];
  float* out = (float*)d_out;

  // Workspace layout (4 B words), ~56 MB total.
  int* deg   = (int*)d_ws;                 // NN16
  int* ptr   = deg + NN16;                 // NN16
  int* blk   = ptr + NN16;                 // 1024
  int* ru    = blk + 1024;                 // E0
  int* ri    = ru + E0;                    // E0
  int* col   = ri + E0;                    // E2
  float* dinv = (float*)(col + E2);        // NN16
  uint2* hA  = (uint2*)(dinv + NN16);      // NNODES*16 uint2 (19.2 MB)
  uint2* hB  = hA + (size_t)NNODES * 16;   // 19.2 MB
  float* gu  = (float*)(hB + (size_t)NNODES * 16);  // BB*64
  float* gp  = gu + BB * DIM;
  float* gn  = gp + BB * DIM;
  float* bpart = gn + BB * DIM;            // 2*LOSS_BLOCKS

  const int T = 256;
  auto cdiv = [](int a, int b) { return (a + b - 1) / b; };

  const float4* Gu4 = (const float4*)Gu;
  const float4* Gi4 = (const float4*)Gi;
  float4* gu4 = (float4*)gu;
  float4* gp4 = (float4*)gp;
  float4* gn4 = (float4*)gn;

  k_zero_i<<<cdiv(NN16, T), T, 0, stream>>>(deg, NN16);
  k_count_deg<<<cdiv(E0, T), T, 0, stream>>>(eu, ei, deg, ru, ri);
  k_scan1<<<NB, 256, 0, stream>>>(deg, ptr, blk);
  k_scan2<<<1, 1024, 0, stream>>>(blk);
  k_scan3<<<NB, 256, 0, stream>>>(ptr, blk, deg, dinv);
  k_place<<<cdiv(E0, T), T, 0, stream>>>(eu, ei, ptr, ru, ri, col);

  k_cast<<<cdiv(NNODES * 16, T), T, 0, stream>>>(Gu4, Gi4, hA);
  k_batch_set<<<cdiv(BB * 16, T), T, 0, stream>>>(usr, pos, neg, Gu4, Gi4, gu4, gp4, gn4);

  // L1: hA -> hB ; L2: hB -> hA ; L3: hA -> hB
  k_spmm_bf<<<cdiv(NNODES, 4), 256, 0, stream>>>(ptr, deg, col, dinv, hA, hB);
  k_batch_add<<<cdiv(BB * 16, T), T, 0, stream>>>(usr, pos, neg, hB, gu4, gp4, gn4);
  k_spmm_bf<<<cdiv(NNODES, 4), 256, 0, stream>>>(ptr, deg, col, dinv, hB, hA);
  k_batch_add<<<cdiv(BB * 16, T), T, 0, stream>>>(usr, pos, neg, hA, gu4, gp4, gn4);
  k_spmm_bf<<<cdiv(NNODES, 4), 256, 0, stream>>>(ptr, deg, col, dinv, hA, hB);
  k_batch_add<<<cdiv(BB * 16, T), T, 0, stream>>>(usr, pos, neg, hB, gu4, gp4, gn4);

  k_loss<<<LOSS_BLOCKS, 256, 0, stream>>>(gu, gp, gn, bpart);
  k_final<<<1, 64, 0, stream>>>(bpart, out);
}

// Round 6
// 345.251 us; speedup vs baseline: 3.3843x; 1.1999x over previous
//
#include <hip/hip_runtime.h>

#define NUSERS 100000
#define NITEMS 50000
#define NNODES 150000
#define DIM 64
#define E0 600000
#define E2 (2 * E0)
#define BB 8192
#define LW 1e-4f
#define NN16 150016
#define NB 586  // cdiv(NNODES, 256)
#define LOSS_BLOCKS 128

// ---- bf16 helpers (fp32 <-> packed bf16 pair in a uint) ----
__device__ __forceinline__ float bf_lo(unsigned u) { return __uint_as_float(u << 16); }
__device__ __forceinline__ float bf_hi(unsigned u) { return __uint_as_float(u & 0xffff0000u); }
__device__ __forceinline__ unsigned rne16(float x) {
  unsigned u = __float_as_uint(x);
  return (u + 0x7fffu + ((u >> 16) & 1u)) >> 16;
}
__device__ __forceinline__ unsigned pack2(float lo, float hi) {
  return rne16(lo) | (rne16(hi) << 16);
}

__global__ void k_zero_i(int* __restrict__ p, int n) {
  int i = blockIdx.x * blockDim.x + threadIdx.x;
  if (i < n) p[i] = 0;
}

// Count degrees; atomic return value IS the edge's rank within its row.
__global__ void k_count_deg(const int* __restrict__ eu, const int* __restrict__ ei,
                            int* __restrict__ deg, int* __restrict__ ru,
                            int* __restrict__ ri) {
  int e = blockIdx.x * blockDim.x + threadIdx.x;
  if (e < E0) {
    ru[e] = atomicAdd(&deg[eu[e]], 1);
    ri[e] = atomicAdd(&deg[NUSERS + ei[e]], 1);
  }
}

// --- 3-kernel exclusive scan over deg -> ptr (row starts) ---
__global__ void k_scan1(const int* __restrict__ deg, int* __restrict__ ptr,
                        int* __restrict__ blk) {
  __shared__ int s[256];
  int g = blockIdx.x * 256 + threadIdx.x;
  int v = (g < NNODES) ? deg[g] : 0;
  s[threadIdx.x] = v;
  __syncthreads();
  for (int off = 1; off < 256; off <<= 1) {
    int t = 0;
    if ((int)threadIdx.x >= off) t = s[threadIdx.x - off];
    __syncthreads();
    if ((int)threadIdx.x >= off) s[threadIdx.x] += t;
    __syncthreads();
  }
  if (g < NNODES) ptr[g] = s[threadIdx.x] - v;
  if (threadIdx.x == 255) blk[blockIdx.x] = s[255];
}

__global__ void k_scan2(int* __restrict__ blk) {
  __shared__ int s[1024];
  int v = ((int)threadIdx.x < NB) ? blk[threadIdx.x] : 0;
  s[threadIdx.x] = v;
  __syncthreads();
  for (int off = 1; off < 1024; off <<= 1) {
    int t = 0;
    if ((int)threadIdx.x >= off) t = s[threadIdx.x - off];
    __syncthreads();
    if ((int)threadIdx.x >= off) s[threadIdx.x] += t;
    __syncthreads();
  }
  if ((int)threadIdx.x < NB) blk[threadIdx.x] = s[threadIdx.x] - v;
}

__global__ void k_scan3(int* __restrict__ ptr, const int* __restrict__ blk,
                        const int* __restrict__ deg, float* __restrict__ dinv) {
  int g = blockIdx.x * 256 + threadIdx.x;
  if (g < NNODES) {
    ptr[g] += blk[blockIdx.x];
    int d = deg[g];
    dinv[g] = d > 0 ? rsqrtf((float)d) : 0.0f;
  }
}

// Place CSR columns using precomputed ranks — NO atomics.
__global__ void k_place(const int* __restrict__ eu, const int* __restrict__ ei,
                        const int* __restrict__ ptr, const int* __restrict__ ru,
                        const int* __restrict__ ri, int* __restrict__ col) {
  int e = blockIdx.x * blockDim.x + threadIdx.x;
  if (e < E0) {
    int u = eu[e];
    int it = NUSERS + ei[e];
    col[ptr[u] + ru[e]] = it;
    col[ptr[it] + ri[e]] = u;
  }
}

// h0 (bf16, concat users|items) from the fp32 inputs.
__global__ void k_cast(const float4* __restrict__ Gu4, const float4* __restrict__ Gi4,
                       uint2* __restrict__ h0) {
  int t = blockIdx.x * blockDim.x + threadIdx.x;
  if (t >= NNODES * 16) return;
  float4 v = (t < NUSERS * 16) ? Gu4[t] : Gi4[t - NUSERS * 16];
  h0[t] = make_uint2(pack2(v.x, v.y), pack2(v.z, v.w));
}

// Gather-only SpMM over ONE bipartite side. One wave per destination node.
// lane = 8*sub + q: sub in [0,8) walks neighbors stride-8 (8 rows in flight),
// q in [0,8) covers the 128 B row in uint4 (16 B) chunks.
// hsrc points at the SOURCE half (row index = col[j] - coff).
__global__ void k_spmm_half(const int* __restrict__ ptr, const int* __restrict__ deg,
                            const int* __restrict__ col, const float* __restrict__ dinv,
                            const uint4* __restrict__ hsrc, uint4* __restrict__ hout,
                            int n0, int ncnt, int coff) {
  int tid = threadIdx.x;
  int w = blockIdx.x * 4 + (tid >> 6);
  if (w >= ncnt) return;
  int n = n0 + w;
  int lane = tid & 63;
  int sub = lane >> 3;
  int q = lane & 7;
  int start = ptr[n];
  int end = start + deg[n];
  float dn = dinv[n];
  float a0 = 0, a1 = 0, a2 = 0, a3 = 0, a4 = 0, a5 = 0, a6 = 0, a7 = 0;
  for (int j = start + sub; j < end; j += 8) {
    int c = col[j];
    float wgt = dn * dinv[c];
    uint4 v = hsrc[(size_t)(c - coff) * 8 + q];
    a0 += wgt * bf_lo(v.x); a1 += wgt * bf_hi(v.x);
    a2 += wgt * bf_lo(v.y); a3 += wgt * bf_hi(v.y);
    a4 += wgt * bf_lo(v.z); a5 += wgt * bf_hi(v.z);
    a6 += wgt * bf_lo(v.w); a7 += wgt * bf_hi(v.w);
  }
  // reduce across the 8 subs (xor masks 8,16,32 keep q fixed)
  #pragma unroll
  for (int m = 8; m <= 32; m <<= 1) {
    a0 += __shfl_xor(a0, m); a1 += __shfl_xor(a1, m);
    a2 += __shfl_xor(a2, m); a3 += __shfl_xor(a3, m);
    a4 += __shfl_xor(a4, m); a5 += __shfl_xor(a5, m);
    a6 += __shfl_xor(a6, m); a7 += __shfl_xor(a7, m);
  }
  if (sub == 0)
    hout[(size_t)n * 8 + q] = make_uint4(pack2(a0, a1), pack2(a2, a3),
                                         pack2(a4, a5), pack2(a6, a7));
}

// Fused batch gather + layer sum + BPR loss. Wave handles 4 batch rows:
// lane = 16*r + q; q covers 4 dims (float4 / uint2). No global atomics.
__global__ void k_loss(const int* __restrict__ usr, const int* __restrict__ pos,
                       const int* __restrict__ neg,
                       const float4* __restrict__ Gu4, const float4* __restrict__ Gi4,
                       const uint2* __restrict__ h1, const uint2* __restrict__ h2,
                       const uint2* __restrict__ h3, float* __restrict__ bpart) {
  __shared__ float sL[4], sR[4];
  int wid = threadIdx.x >> 6;
  int lane = threadIdx.x & 63;
  int r = lane >> 4;
  int q = lane & 15;
  int gw = blockIdx.x * 4 + wid;
  int nw = gridDim.x * 4;
  const float s = 0.25f;
  float accL = 0.0f, accR = 0.0f;
  for (int b4 = gw; b4 < BB / 4; b4 += nw) {
    int b = b4 * 4 + r;
    int iu = usr[b], ip = pos[b], ig = neg[b];
    size_t ou = (size_t)iu * 16 + q;
    size_t op = ((size_t)NUSERS + ip) * 16 + q;
    size_t on = ((size_t)NUSERS + ig) * 16 + q;
    float4 u = Gu4[ou - q + q];  // = Gu4[iu*16+q]
    float4 p = Gi4[(size_t)ip * 16 + q];
    float4 g = Gi4[(size_t)ig * 16 + q];
    uint2 v;
    v = h1[ou]; u.x += bf_lo(v.x); u.y += bf_hi(v.x); u.z += bf_lo(v.y); u.w += bf_hi(v.y);
    v = h2[ou]; u.x += bf_lo(v.x); u.y += bf_hi(v.x); u.z += bf_lo(v.y); u.w += bf_hi(v.y);
    v = h3[ou]; u.x += bf_lo(v.x); u.y += bf_hi(v.x); u.z += bf_lo(v.y); u.w += bf_hi(v.y);
    v = h1[op]; p.x += bf_lo(v.x); p.y += bf_hi(v.x); p.z += bf_lo(v.y); p.w += bf_hi(v.y);
    v = h2[op]; p.x += bf_lo(v.x); p.y += bf_hi(v.x); p.z += bf_lo(v.y); p.w += bf_hi(v.y);
    v = h3[op]; p.x += bf_lo(v.x); p.y += bf_hi(v.x); p.z += bf_lo(v.y); p.w += bf_hi(v.y);
    v = h1[on]; g.x += bf_lo(v.x); g.y += bf_hi(v.x); g.z += bf_lo(v.y); g.w += bf_hi(v.y);
    v = h2[on]; g.x += bf_lo(v.x); g.y += bf_hi(v.x); g.z += bf_lo(v.y); g.w += bf_hi(v.y);
    v = h3[on]; g.x += bf_lo(v.x); g.y += bf_hi(v.x); g.z += bf_lo(v.y); g.w += bf_hi(v.y);
    u.x *= s; u.y *= s; u.z *= s; u.w *= s;
    p.x *= s; p.y *= s; p.z *= s; p.w *= s;
    g.x *= s; g.y *= s; g.z *= s; g.w *= s;
    float dp = u.x * p.x + u.y * p.y + u.z * p.z + u.w * p.w;
    float dn = u.x * g.x + u.y * g.y + u.z * g.z + u.w * g.w;
    float rg = u.x * u.x + u.y * u.y + u.z * u.z + u.w * u.w
             + p.x * p.x + p.y * p.y + p.z * p.z + p.w * p.w
             + g.x * g.x + g.y * g.y + g.z * g.z + g.w * g.w;
    #pragma unroll
    for (int m = 1; m <= 8; m <<= 1) {
      dp += __shfl_xor(dp, m);
      dn += __shfl_xor(dn, m);
      rg += __shfl_xor(rg, m);
    }
    if (q == 0) {
      float diff = dp - dn;
      accL -= fminf(diff, 0.0f) - log1pf(expf(-fabsf(diff)));
      accR += rg;
    }
  }
  // collapse the 4 r-partials (lanes 0,16,32,48)
  accL += __shfl_xor(accL, 16); accR += __shfl_xor(accR, 16);
  accL += __shfl_xor(accL, 32); accR += __shfl_xor(accR, 32);
  if (lane == 0) { sL[wid] = accL; sR[wid] = accR; }
  __syncthreads();
  if (threadIdx.x == 0) {
    bpart[blockIdx.x] = sL[0] + sL[1] + sL[2] + sL[3];
    bpart[LOSS_BLOCKS + blockIdx.x] = sR[0] + sR[1] + sR[2] + sR[3];
  }
}

__global__ void k_final(const float* __restrict__ bpart, float* __restrict__ out) {
  int lane = threadIdx.x;
  float l = bpart[lane] + bpart[lane + 64];
  float r = bpart[LOSS_BLOCKS + lane] + bpart[LOSS_BLOCKS + lane + 64];
  for (int off = 32; off > 0; off >>= 1) {
    l += __shfl_down(l, off);
    r += __shfl_down(r, off);
  }
  if (lane == 0) out[0] = l * (1.0f / BB) + LW * 0.5f * r * (1.0f / BB);
}

extern "C" void kernel_launch(void* const* d_in, const int* in_sizes, int n_in,
                              void* d_out, int out_size, void* d_ws, size_t ws_size,
                              hipStream_t stream) {
  const float* Gu = (const float*)d_in[0];
  const float* Gi = (const float*)d_in[1];
  const int* eu  = (const int*)d_in[2];
  const int* ei  = (const int*)d_in[3];
  const int* usr = (const int*)d_in[4];
  const int* pos = (const int*)d_in[5];
  const int* neg = (const int*)d_in[6];
  float* out = (float*)d_out;

  // Workspace layout (4 B words): ~11.4 MB ints + 76.8 MB h = ~88.3 MB.
  int* deg   = (int*)d_ws;                 // NN16
  int* ptr   = deg + NN16;                 // NN16
  int* blk   = ptr + NN16;                 // 1024
  int* ru    = blk + 1024;                 // E0
  int* ri    = ru + E0;                    // E0
  int* col   = ri + E0;                    // E2
  float* dinv = (float*)(col + E2);        // NN16
  uint2* h0  = (uint2*)(dinv + NN16);      // NNODES*16 uint2 each (19.2 MB)
  uint2* h1  = h0 + (size_t)NNODES * 16;
  uint2* h2  = h1 + (size_t)NNODES * 16;
  uint2* h3  = h2 + (size_t)NNODES * 16;
  float* bpart = (float*)(h3 + (size_t)NNODES * 16);  // 2*LOSS_BLOCKS

  const int T = 256;
  auto cdiv = [](int a, int b) { return (a + b - 1) / b; };

  k_zero_i<<<cdiv(NN16, T), T, 0, stream>>>(deg, NN16);
  k_count_deg<<<cdiv(E0, T), T, 0, stream>>>(eu, ei, deg, ru, ri);
  k_scan1<<<NB, 256, 0, stream>>>(deg, ptr, blk);
  k_scan2<<<1, 1024, 0, stream>>>(blk);
  k_scan3<<<NB, 256, 0, stream>>>(ptr, blk, deg, dinv);
  k_place<<<cdiv(E0, T), T, 0, stream>>>(eu, ei, ptr, ru, ri, col);

  const float4* Gu4 = (const float4*)Gu;
  const float4* Gi4 = (const float4*)Gi;
  k_cast<<<cdiv(NNODES * 16, T), T, 0, stream>>>(Gu4, Gi4, h0);

  const size_t IOFF4 = (size_t)NUSERS * 8;  // item half offset in uint4 units
  uint2* hs[4] = {h0, h1, h2, h3};
  for (int l = 0; l < 3; ++l) {
    const uint4* hin = (const uint4*)hs[l];
    uint4* hout = (uint4*)hs[l + 1];
    // user destinations gather from the item half; item dst from the user half
    k_spmm_half<<<cdiv(NUSERS, 4), 256, 0, stream>>>(ptr, deg, col, dinv,
                                                     hin + IOFF4, hout, 0, NUSERS, NUSERS);
    k_spmm_half<<<cdiv(NITEMS, 4), 256, 0, stream>>>(ptr, deg, col, dinv,
                                                     hin, hout, NUSERS, NITEMS, 0);
  }

  k_loss<<<LOSS_BLOCKS, 256, 0, stream>>>(usr, pos, neg, Gu4, Gi4, h1, h2, h3, bpart);
  k_final<<<1, 64, 0, stream>>>(bpart, out);
}

// Round 7
// 276.856 us; speedup vs baseline: 4.2204x; 1.2470x over previous
//
#include <hip/hip_runtime.h>

#define NUSERS 100000
#define NITEMS 50000
#define NNODES 150000
#define DIM 64
#define E0 600000
#define E2 (2 * E0)
#define BB 8192
#define LW 1e-4f
#define NN16 150016
#define NB 586      // cdiv(NNODES, 256)
#define LOSS_BLOCKS 128
#define UBLK 6250   // cdiv(NUSERS, 16)  (16 nodes per 512-thr block)
#define IBLK 3125   // cdiv(NITEMS, 16)
#define PLACE_B 2344  // cdiv(E0, 256)
#define CAST_B 9375   // cdiv(NNODES*16, 256)

// ---- bf16 helpers (fp32 <-> packed bf16 pair in a uint) ----
__device__ __forceinline__ float bf_lo(unsigned u) { return __uint_as_float(u << 16); }
__device__ __forceinline__ float bf_hi(unsigned u) { return __uint_as_float(u & 0xffff0000u); }
__device__ __forceinline__ unsigned rne16(float x) {
  unsigned u = __float_as_uint(x);
  return (u + 0x7fffu + ((u >> 16) & 1u)) >> 16;
}
__device__ __forceinline__ unsigned pack2(float lo, float hi) {
  return rne16(lo) | (rne16(hi) << 16);
}

__global__ void k_zero_i(int* __restrict__ p, int n) {
  int i = blockIdx.x * blockDim.x + threadIdx.x;
  if (i < n) p[i] = 0;
}

// Count degrees; atomic return value IS the edge's rank within its row.
// ~52us: 1.2M device-scope fabric atomics at ~23 G/s — op-rate floor.
__global__ void k_count_deg(const int* __restrict__ eu, const int* __restrict__ ei,
                            int* __restrict__ deg, int* __restrict__ ru,
                            int* __restrict__ ri) {
  int e = blockIdx.x * blockDim.x + threadIdx.x;
  if (e < E0) {
    ru[e] = atomicAdd(&deg[eu[e]], 1);
    ri[e] = atomicAdd(&deg[NUSERS + ei[e]], 1);
  }
}

// --- 3-kernel exclusive scan over deg -> ptr (row starts) ---
__global__ void k_scan1(const int* __restrict__ deg, int* __restrict__ ptr,
                        int* __restrict__ blk) {
  __shared__ int s[256];
  int g = blockIdx.x * 256 + threadIdx.x;
  int v = (g < NNODES) ? deg[g] : 0;
  s[threadIdx.x] = v;
  __syncthreads();
  for (int off = 1; off < 256; off <<= 1) {
    int t = 0;
    if ((int)threadIdx.x >= off) t = s[threadIdx.x - off];
    __syncthreads();
    if ((int)threadIdx.x >= off) s[threadIdx.x] += t;
    __syncthreads();
  }
  if (g < NNODES) ptr[g] = s[threadIdx.x] - v;
  if (threadIdx.x == 255) blk[blockIdx.x] = s[255];
}

__global__ void k_scan2(int* __restrict__ blk) {
  __shared__ int s[1024];
  int v = ((int)threadIdx.x < NB) ? blk[threadIdx.x] : 0;
  s[threadIdx.x] = v;
  __syncthreads();
  for (int off = 1; off < 1024; off <<= 1) {
    int t = 0;
    if ((int)threadIdx.x >= off) t = s[threadIdx.x - off];
    __syncthreads();
    if ((int)threadIdx.x >= off) s[threadIdx.x] += t;
    __syncthreads();
  }
  if ((int)threadIdx.x < NB) blk[threadIdx.x] = s[threadIdx.x] - v;
}

__global__ void k_scan3(int* __restrict__ ptr, const int* __restrict__ blk,
                        const int* __restrict__ deg, float* __restrict__ dinv) {
  int g = blockIdx.x * 256 + threadIdx.x;
  if (g < NNODES) {
    ptr[g] += blk[blockIdx.x];
    int d = deg[g];
    dinv[g] = d > 0 ? rsqrtf((float)d) : 0.0f;
  }
}

// Fused: CSR column placement (no atomics) + scaled-cast s0 = dinv*h0 (bf16).
// Block-range split; cast's streaming hides behind place's scattered stores.
__global__ void k_place_cast(const int* __restrict__ eu, const int* __restrict__ ei,
                             const int* __restrict__ ptr, const int* __restrict__ ru,
                             const int* __restrict__ ri, int* __restrict__ col,
                             const float4* __restrict__ Gu4, const float4* __restrict__ Gi4,
                             const float* __restrict__ dinv, uint2* __restrict__ h0) {
  int b = blockIdx.x;
  if (b < PLACE_B) {
    int e = b * 256 + threadIdx.x;
    if (e < E0) {
      int u = eu[e];
      int it = NUSERS + ei[e];
      col[ptr[u] + ru[e]] = it;
      col[ptr[it] + ri[e]] = u;
    }
  } else {
    int t = (b - PLACE_B) * 256 + threadIdx.x;
    if (t < NNODES * 16) {
      int node = t >> 4;
      float dv = dinv[node];
      float4 v = (t < NUSERS * 16) ? Gu4[t] : Gi4[t - NUSERS * 16];
      h0[t] = make_uint2(pack2(dv * v.x, dv * v.y), pack2(dv * v.z, dv * v.w));
    }
  }
}

// Scaled-space SpMM: s_out(n) = dinv(n)^2 * sum_{c in N(n)} s_in(c).
// No per-neighbor weights (deleted dinv[c] gather). 2 nodes per wave for MLP.
// lane = 8*sub + q: sub walks neighbors stride-8, q covers row in uint4 chunks.
__global__ __launch_bounds__(512) void k_spmm2(
    const int* __restrict__ ptr, const int* __restrict__ deg,
    const int* __restrict__ col, const float* __restrict__ dinv,
    const uint4* __restrict__ h, uint4* __restrict__ hout) {
  int wid = threadIdx.x >> 6;
  int lane = threadIdx.x & 63;
  int sub = lane >> 3;
  int q = lane & 7;
  int gA, coff;
  const uint4* hsrc;
  if (blockIdx.x < UBLK) {           // user destinations gather from item half
    gA = blockIdx.x * 16 + wid * 2;
    coff = NUSERS;
    hsrc = h + (size_t)NUSERS * 8;
  } else {                            // item destinations gather from user half
    gA = NUSERS + (blockIdx.x - UBLK) * 16 + wid * 2;
    coff = 0;
    hsrc = h;
  }
  int gB = gA + 1;
  int stA = ptr[gA], dgA = deg[gA];
  int stB = ptr[gB], dgB = deg[gB];
  float dnA = dinv[gA], dnB = dinv[gB];
  int cA = (sub < dgA) ? col[stA + sub] : -1;
  int cB = (sub < dgB) ? col[stB + sub] : -1;
  uint4 xA = {0, 0, 0, 0}, xB = {0, 0, 0, 0};
  if (cA >= 0) xA = hsrc[(size_t)(cA - coff) * 8 + q];
  if (cB >= 0) xB = hsrc[(size_t)(cB - coff) * 8 + q];
  float aA0 = bf_lo(xA.x), aA1 = bf_hi(xA.x), aA2 = bf_lo(xA.y), aA3 = bf_hi(xA.y);
  float aA4 = bf_lo(xA.z), aA5 = bf_hi(xA.z), aA6 = bf_lo(xA.w), aA7 = bf_hi(xA.w);
  float aB0 = bf_lo(xB.x), aB1 = bf_hi(xB.x), aB2 = bf_lo(xB.y), aB3 = bf_hi(xB.y);
  float aB4 = bf_lo(xB.z), aB5 = bf_hi(xB.z), aB6 = bf_lo(xB.w), aB7 = bf_hi(xB.w);
  for (int j = stA + 8 + sub; j < stA + dgA; j += 8) {
    int c = col[j];
    uint4 x = hsrc[(size_t)(c - coff) * 8 + q];
    aA0 += bf_lo(x.x); aA1 += bf_hi(x.x); aA2 += bf_lo(x.y); aA3 += bf_hi(x.y);
    aA4 += bf_lo(x.z); aA5 += bf_hi(x.z); aA6 += bf_lo(x.w); aA7 += bf_hi(x.w);
  }
  for (int j = stB + 8 + sub; j < stB + dgB; j += 8) {
    int c = col[j];
    uint4 x = hsrc[(size_t)(c - coff) * 8 + q];
    aB0 += bf_lo(x.x); aB1 += bf_hi(x.x); aB2 += bf_lo(x.y); aB3 += bf_hi(x.y);
    aB4 += bf_lo(x.z); aB5 += bf_hi(x.z); aB6 += bf_lo(x.w); aB7 += bf_hi(x.w);
  }
  #pragma unroll
  for (int m = 8; m <= 32; m <<= 1) {
    aA0 += __shfl_xor(aA0, m); aA1 += __shfl_xor(aA1, m);
    aA2 += __shfl_xor(aA2, m); aA3 += __shfl_xor(aA3, m);
    aA4 += __shfl_xor(aA4, m); aA5 += __shfl_xor(aA5, m);
    aA6 += __shfl_xor(aA6, m); aA7 += __shfl_xor(aA7, m);
    aB0 += __shfl_xor(aB0, m); aB1 += __shfl_xor(aB1, m);
    aB2 += __shfl_xor(aB2, m); aB3 += __shfl_xor(aB3, m);
    aB4 += __shfl_xor(aB4, m); aB5 += __shfl_xor(aB5, m);
    aB6 += __shfl_xor(aB6, m); aB7 += __shfl_xor(aB7, m);
  }
  if (sub == 0) {
    float sA = dnA * dnA;
    float sB = dnB * dnB;
    hout[(size_t)gA * 8 + q] = make_uint4(pack2(aA0 * sA, aA1 * sA), pack2(aA2 * sA, aA3 * sA),
                                          pack2(aA4 * sA, aA5 * sA), pack2(aA6 * sA, aA7 * sA));
    hout[(size_t)gB * 8 + q] = make_uint4(pack2(aB0 * sB, aB1 * sB), pack2(aB2 * sB, aB3 * sB),
                                          pack2(aB4 * sB, aB5 * sB), pack2(aB6 * sB, aB7 * sB));
  }
}

__device__ __forceinline__ int decode_node(int k, const int* __restrict__ usr,
                                           const int* __restrict__ pos,
                                           const int* __restrict__ neg, int* coff) {
  if (k < BB) { *coff = NUSERS; return usr[k]; }
  if (k < 2 * BB) { *coff = 0; return NUSERS + pos[k - BB]; }
  *coff = 0; return NUSERS + neg[k - 2 * BB];
}

// Layer-3 SpMM only at the <=3*BB batch nodes (duplicates write identical
// values — benign). Same 2-nodes-per-wave structure.
__global__ __launch_bounds__(512) void k_spmm_batch(
    const int* __restrict__ usr, const int* __restrict__ pos, const int* __restrict__ neg,
    const int* __restrict__ ptr, const int* __restrict__ deg,
    const int* __restrict__ col, const float* __restrict__ dinv,
    const uint4* __restrict__ h, uint4* __restrict__ hout) {
  int wid = threadIdx.x >> 6;
  int lane = threadIdx.x & 63;
  int sub = lane >> 3;
  int q = lane & 7;
  int k0 = blockIdx.x * 16 + wid * 2;
  int cofA, cofB;
  int gA = decode_node(k0, usr, pos, neg, &cofA);
  int gB = decode_node(k0 + 1, usr, pos, neg, &cofB);
  const uint4* hsA = h + (size_t)cofA * 8;
  const uint4* hsB = h + (size_t)cofB * 8;
  int stA = ptr[gA], dgA = deg[gA];
  int stB = ptr[gB], dgB = deg[gB];
  float dnA = dinv[gA], dnB = dinv[gB];
  int cA = (sub < dgA) ? col[stA + sub] : -1;
  int cB = (sub < dgB) ? col[stB + sub] : -1;
  uint4 xA = {0, 0, 0, 0}, xB = {0, 0, 0, 0};
  if (cA >= 0) xA = hsA[(size_t)(cA - cofA) * 8 + q];
  if (cB >= 0) xB = hsB[(size_t)(cB - cofB) * 8 + q];
  float aA0 = bf_lo(xA.x), aA1 = bf_hi(xA.x), aA2 = bf_lo(xA.y), aA3 = bf_hi(xA.y);
  float aA4 = bf_lo(xA.z), aA5 = bf_hi(xA.z), aA6 = bf_lo(xA.w), aA7 = bf_hi(xA.w);
  float aB0 = bf_lo(xB.x), aB1 = bf_hi(xB.x), aB2 = bf_lo(xB.y), aB3 = bf_hi(xB.y);
  float aB4 = bf_lo(xB.z), aB5 = bf_hi(xB.z), aB6 = bf_lo(xB.w), aB7 = bf_hi(xB.w);
  for (int j = stA + 8 + sub; j < stA + dgA; j += 8) {
    int c = col[j];
    uint4 x = hsA[(size_t)(c - cofA) * 8 + q];
    aA0 += bf_lo(x.x); aA1 += bf_hi(x.x); aA2 += bf_lo(x.y); aA3 += bf_hi(x.y);
    aA4 += bf_lo(x.z); aA5 += bf_hi(x.z); aA6 += bf_lo(x.w); aA7 += bf_hi(x.w);
  }
  for (int j = stB + 8 + sub; j < stB + dgB; j += 8) {
    int c = col[j];
    uint4 x = hsB[(size_t)(c - cofB) * 8 + q];
    aB0 += bf_lo(x.x); aB1 += bf_hi(x.x); aB2 += bf_lo(x.y); aB3 += bf_hi(x.y);
    aB4 += bf_lo(x.z); aB5 += bf_hi(x.z); aB6 += bf_lo(x.w); aB7 += bf_hi(x.w);
  }
  #pragma unroll
  for (int m = 8; m <= 32; m <<= 1) {
    aA0 += __shfl_xor(aA0, m); aA1 += __shfl_xor(aA1, m);
    aA2 += __shfl_xor(aA2, m); aA3 += __shfl_xor(aA3, m);
    aA4 += __shfl_xor(aA4, m); aA5 += __shfl_xor(aA5, m);
    aA6 += __shfl_xor(aA6, m); aA7 += __shfl_xor(aA7, m);
    aB0 += __shfl_xor(aB0, m); aB1 += __shfl_xor(aB1, m);
    aB2 += __shfl_xor(aB2, m); aB3 += __shfl_xor(aB3, m);
    aB4 += __shfl_xor(aB4, m); aB5 += __shfl_xor(aB5, m);
    aB6 += __shfl_xor(aB6, m); aB7 += __shfl_xor(aB7, m);
  }
  if (sub == 0) {
    float sA = dnA * dnA;
    float sB = dnB * dnB;
    hout[(size_t)gA * 8 + q] = make_uint4(pack2(aA0 * sA, aA1 * sA), pack2(aA2 * sA, aA3 * sA),
                                          pack2(aA4 * sA, aA5 * sA), pack2(aA6 * sA, aA7 * sA));
    hout[(size_t)gB * 8 + q] = make_uint4(pack2(aB0 * sB, aB1 * sB), pack2(aB2 * sB, aB3 * sB),
                                          pack2(aB4 * sB, aB5 * sB), pack2(aB6 * sB, aB7 * sB));
  }
}

// Fused batch gather + layer sum + BPR loss; h_l = sqrt(deg)*s_l.
__global__ void k_loss(const int* __restrict__ usr, const int* __restrict__ pos,
                       const int* __restrict__ neg, const int* __restrict__ deg,
                       const float4* __restrict__ Gu4, const float4* __restrict__ Gi4,
                       const uint2* __restrict__ h1, const uint2* __restrict__ h2,
                       const uint2* __restrict__ h3, float* __restrict__ bpart) {
  __shared__ float sL[4], sR[4];
  int wid = threadIdx.x >> 6;
  int lane = threadIdx.x & 63;
  int r = lane >> 4;
  int q = lane & 15;
  int gw = blockIdx.x * 4 + wid;
  int nw = gridDim.x * 4;
  const float s = 0.25f;
  float accL = 0.0f, accR = 0.0f;
  for (int b4 = gw; b4 < BB / 4; b4 += nw) {
    int b = b4 * 4 + r;
    int iu = usr[b], ip = pos[b], ig = neg[b];
    float sdu = sqrtf((float)deg[iu]);
    float sdp = sqrtf((float)deg[NUSERS + ip]);
    float sdn = sqrtf((float)deg[NUSERS + ig]);
    size_t ou = (size_t)iu * 16 + q;
    size_t op = ((size_t)NUSERS + ip) * 16 + q;
    size_t on = ((size_t)NUSERS + ig) * 16 + q;
    float4 u = Gu4[ou];
    float4 p = Gi4[(size_t)ip * 16 + q];
    float4 g = Gi4[(size_t)ig * 16 + q];
    float4 su = {0, 0, 0, 0}, sp = {0, 0, 0, 0}, sg = {0, 0, 0, 0};
    uint2 v;
    v = h1[ou]; su.x += bf_lo(v.x); su.y += bf_hi(v.x); su.z += bf_lo(v.y); su.w += bf_hi(v.y);
    v = h2[ou]; su.x += bf_lo(v.x); su.y += bf_hi(v.x); su.z += bf_lo(v.y); su.w += bf_hi(v.y);
    v = h3[ou]; su.x += bf_lo(v.x); su.y += bf_hi(v.x); su.z += bf_lo(v.y); su.w += bf_hi(v.y);
    v = h1[op]; sp.x += bf_lo(v.x); sp.y += bf_hi(v.x); sp.z += bf_lo(v.y); sp.w += bf_hi(v.y);
    v = h2[op]; sp.x += bf_lo(v.x); sp.y += bf_hi(v.x); sp.z += bf_lo(v.y); sp.w += bf_hi(v.y);
    v = h3[op]; sp.x += bf_lo(v.x); sp.y += bf_hi(v.x); sp.z += bf_lo(v.y); sp.w += bf_hi(v.y);
    v = h1[on]; sg.x += bf_lo(v.x); sg.y += bf_hi(v.x); sg.z += bf_lo(v.y); sg.w += bf_hi(v.y);
    v = h2[on]; sg.x += bf_lo(v.x); sg.y += bf_hi(v.x); sg.z += bf_lo(v.y); sg.w += bf_hi(v.y);
    v = h3[on]; sg.x += bf_lo(v.x); sg.y += bf_hi(v.x); sg.z += bf_lo(v.y); sg.w += bf_hi(v.y);
    u.x = (u.x + sdu * su.x) * s; u.y = (u.y + sdu * su.y) * s;
    u.z = (u.z + sdu * su.z) * s; u.w = (u.w + sdu * su.w) * s;
    p.x = (p.x + sdp * sp.x) * s; p.y = (p.y + sdp * sp.y) * s;
    p.z = (p.z + sdp * sp.z) * s; p.w = (p.w + sdp * sp.w) * s;
    g.x = (g.x + sdn * sg.x) * s; g.y = (g.y + sdn * sg.y) * s;
    g.z = (g.z + sdn * sg.z) * s; g.w = (g.w + sdn * sg.w) * s;
    float dp = u.x * p.x + u.y * p.y + u.z * p.z + u.w * p.w;
    float dn = u.x * g.x + u.y * g.y + u.z * g.z + u.w * g.w;
    float rg = u.x * u.x + u.y * u.y + u.z * u.z + u.w * u.w
             + p.x * p.x + p.y * p.y + p.z * p.z + p.w * p.w
             + g.x * g.x + g.y * g.y + g.z * g.z + g.w * g.w;
    #pragma unroll
    for (int m = 1; m <= 8; m <<= 1) {
      dp += __shfl_xor(dp, m);
      dn += __shfl_xor(dn, m);
      rg += __shfl_xor(rg, m);
    }
    if (q == 0) {
      float diff = dp - dn;
      accL -= fminf(diff, 0.0f) - log1pf(expf(-fabsf(diff)));
      accR += rg;
    }
  }
  accL += __shfl_xor(accL, 16); accR += __shfl_xor(accR, 16);
  accL += __shfl_xor(accL, 32); accR += __shfl_xor(accR, 32);
  if (lane == 0) { sL[wid] = accL; sR[wid] = accR; }
  __syncthreads();
  if (threadIdx.x == 0) {
    bpart[blockIdx.x] = sL[0] + sL[1] + sL[2] + sL[3];
    bpart[LOSS_BLOCKS + blockIdx.x] = sR[0] + sR[1] + sR[2] + sR[3];
  }
}

__global__ void k_final(const float* __restrict__ bpart, float* __restrict__ out) {
  int lane = threadIdx.x;
  float l = bpart[lane] + bpart[lane + 64];
  float r = bpart[LOSS_BLOCKS + lane] + bpart[LOSS_BLOCKS + lane + 64];
  for (int off = 32; off > 0; off >>= 1) {
    l += __shfl_down(l, off);
    r += __shfl_down(r, off);
  }
  if (lane == 0) out[0] = l * (1.0f / BB) + LW * 0.5f * r * (1.0f / BB);
}

extern "C" void kernel_launch(void* const* d_in, const int* in_sizes, int n_in,
                              void* d_out, int out_size, void* d_ws, size_t ws_size,
                              hipStream_t stream) {
  const float* Gu = (const float*)d_in[0];
  const float* Gi = (const float*)d_in[1];
  const int* eu  = (const int*)d_in[2];
  const int* ei  = (const int*)d_in[3];
  const int* usr = (const int*)d_in[4];
  const int* pos = (const int*)d_in[5];
  const int* neg = (const int*)d_in[6];
  float* out = (float*)d_out;

  // Workspace: ~11.4 MB ints + 76.8 MB s-buffers = ~88.2 MB (same as R6).
  int* deg   = (int*)d_ws;                 // NN16
  int* ptr   = deg + NN16;                 // NN16
  int* blk   = ptr + NN16;                 // 1024
  int* ru    = blk + 1024;                 // E0
  int* ri    = ru + E0;                    // E0
  int* col   = ri + E0;                    // E2
  float* dinv = (float*)(col + E2);        // NN16
  uint2* h0  = (uint2*)(dinv + NN16);      // NNODES*16 uint2 each (19.2 MB)
  uint2* h1  = h0 + (size_t)NNODES * 16;
  uint2* h2  = h1 + (size_t)NNODES * 16;
  uint2* h3  = h2 + (size_t)NNODES * 16;
  float* bpart = (float*)(h3 + (size_t)NNODES * 16);  // 2*LOSS_BLOCKS

  const int T = 256;
  auto cdiv = [](int a, int b) { return (a + b - 1) / b; };

  const float4* Gu4 = (const float4*)Gu;
  const float4* Gi4 = (const float4*)Gi;

  k_zero_i<<<cdiv(NN16, T), T, 0, stream>>>(deg, NN16);
  k_count_deg<<<cdiv(E0, T), T, 0, stream>>>(eu, ei, deg, ru, ri);
  k_scan1<<<NB, 256, 0, stream>>>(deg, ptr, blk);
  k_scan2<<<1, 1024, 0, stream>>>(blk);
  k_scan3<<<NB, 256, 0, stream>>>(ptr, blk, deg, dinv);
  k_place_cast<<<PLACE_B + CAST_B, 256, 0, stream>>>(eu, ei, ptr, ru, ri, col,
                                                     Gu4, Gi4, dinv, h0);

  k_spmm2<<<UBLK + IBLK, 512, 0, stream>>>(ptr, deg, col, dinv,
                                           (const uint4*)h0, (uint4*)h1);
  k_spmm2<<<UBLK + IBLK, 512, 0, stream>>>(ptr, deg, col, dinv,
                                           (const uint4*)h1, (uint4*)h2);
  k_spmm_batch<<<(3 * BB) / 16, 512, 0, stream>>>(usr, pos, neg, ptr, deg, col, dinv,
                                                  (const uint4*)h2, (uint4*)h3);

  k_loss<<<LOSS_BLOCKS, 256, 0, stream>>>(usr, pos, neg, deg, Gu4, Gi4, h1, h2, h3, bpart);
  k_final<<<1, 64, 0, stream>>>(bpart, out);
}